// Round 4
// baseline (152.941 us; speedup 1.0000x reference)
//
#include <hip/hip_runtime.h>

// Problem constants
#define BB 8192
#define CC 4096
#define GG 16
#define SS 256
#define RR 512
#define NN (GG*RR)   // 8192 output cols
#define RPB 4        // rows per prep block

typedef __bf16 bf16x8 __attribute__((ext_vector_type(8)));
typedef float  f32x4_t __attribute__((ext_vector_type(4)));

__device__ __forceinline__ void gld_lds16(const void* g, void* l){
  __builtin_amdgcn_global_load_lds((const __attribute__((address_space(1))) void*)g,
                                   (__attribute__((address_space(3))) void*)l, 16, 0, 0);
}

// ---------------- Pass 1: fused {4-row pipelined gather+cast} and {W cast} --
// Blocks 0..2047: permute+cast 4 x-rows each (double-buffered LDS halves,
// global_load_lds staging, counted vmcnt). Blocks 2048..3071: cast W chunk.
__global__ void __launch_bounds__(256) prep_kernel(
    const float* __restrict__ x, const int* __restrict__ perm,
    const float* __restrict__ W,
    unsigned short* __restrict__ xp, unsigned short* __restrict__ Wb)
{
  __shared__ float rows[2][CC];        // 2 x 16 KB halves
  const int tid = threadIdx.x;
  const int bid = blockIdx.x;
  if (bid < BB/RPB) {
    const size_t b0 = (size_t)bid * RPB;
    // This thread's 16 permutation indices (two bf16x8 output groups).
    const int j0 = tid<<3, j1 = (256+tid)<<3;
    const int4 pa = *(const int4*)(perm + j0);
    const int4 pb = *(const int4*)(perm + j0 + 4);
    const int4 pc = *(const int4*)(perm + j1);
    const int4 pd = *(const int4*)(perm + j1 + 4);

    auto STAGE = [&](int r){
      const float* src = x + (b0+r)*CC;
      float* dst = rows[r&1];
      #pragma unroll
      for (int c=0;c<4;++c){
        const int i = (c<<8)+tid;      // 16B chunk 0..1023
        gld_lds16(src + (i<<2), dst + (i<<2));
      }
    };

    STAGE(0);
    #pragma unroll
    for (int r=0;r<RPB;++r){
      if (r+1<RPB){
        STAGE(r+1);
        asm volatile("s_waitcnt vmcnt(4)" ::: "memory");
      } else {
        asm volatile("s_waitcnt vmcnt(0)" ::: "memory");
      }
      __builtin_amdgcn_s_barrier();    // row r fully landed
      const float* rb = rows[r&1];
      unsigned short* xo = xp + (b0+r)*CC;
      bf16x8 v0, v1;
      v0[0]=(__bf16)rb[pa.x]; v0[1]=(__bf16)rb[pa.y];
      v0[2]=(__bf16)rb[pa.z]; v0[3]=(__bf16)rb[pa.w];
      v0[4]=(__bf16)rb[pb.x]; v0[5]=(__bf16)rb[pb.y];
      v0[6]=(__bf16)rb[pb.z]; v0[7]=(__bf16)rb[pb.w];
      __builtin_nontemporal_store(v0, (bf16x8*)(xo + j0));
      v1[0]=(__bf16)rb[pc.x]; v1[1]=(__bf16)rb[pc.y];
      v1[2]=(__bf16)rb[pc.z]; v1[3]=(__bf16)rb[pc.w];
      v1[4]=(__bf16)rb[pd.x]; v1[5]=(__bf16)rb[pd.y];
      v1[6]=(__bf16)rb[pd.z]; v1[7]=(__bf16)rb[pd.w];
      __builtin_nontemporal_store(v1, (bf16x8*)(xo + j1));
      __builtin_amdgcn_s_barrier();    // reads of this half done before reuse
    }
  } else {
    const int i = (((bid - BB/RPB)<<8) + tid)<<3;
    const float4 f0 = ((const float4*)(W+i))[0];
    const float4 f1 = ((const float4*)(W+i))[1];
    bf16x8 v;
    v[0]=(__bf16)f0.x; v[1]=(__bf16)f0.y; v[2]=(__bf16)f0.z; v[3]=(__bf16)f0.w;
    v[4]=(__bf16)f1.x; v[5]=(__bf16)f1.y; v[6]=(__bf16)f1.z; v[7]=(__bf16)f1.w;
    __builtin_nontemporal_store(v, (bf16x8*)(Wb+i));
  }
}

// ---------------- Pass 2: grouped GEMM, 128x128 tile, K=256 -----------------
// 8 waves (2 row x 4 col), double-buffered LDS, counted vmcnt (T4),
// LDS XOR-swizzle (T2, both-sides), XCD-bijective block map (T1),
// nontemporal epilogue stores (preserve A-panel L2 residency).
__global__ void __launch_bounds__(512, 4) gemm_kernel(
    const unsigned short* __restrict__ xp, const unsigned short* __restrict__ Wb,
    const float* __restrict__ bias, float* __restrict__ out)
{
  __shared__ unsigned short lA[2][128*64];
  __shared__ unsigned short lB[2][128*64];
  const int tid  = threadIdx.x;
  const int lane = tid & 63;
  const int w    = tid >> 6;
  const int wr   = w >> 2;          // 0..1  (64 out rows each)
  const int wc   = w & 3;           // 0..3  (32 out cols each)
  const int l15  = lane & 15, lh = lane >> 4;

  // XCD-aware block mapping: nwg=4096, 512 per XCD, bx-octet per XCD.
  const int bid   = blockIdx.x;
  const int xcd   = bid & 7;
  const int local = bid >> 3;                   // 0..511
  const int bx    = (xcd << 3) + (local & 7);   // 8 n-tiles = 2 groups per XCD
  const int by    = local >> 3;                 // 0..63

  const int m0 = by << 7;
  const int n0 = bx << 7;
  const int g  = bx >> 2;
  const size_t arow0 = (size_t)m0*CC + (size_t)g*SS;
  const size_t brow0 = (size_t)n0*SS;

  f32x4_t acc[4][2];
  #pragma unroll
  for (int i=0;i<4;++i)
    #pragma unroll
    for (int j=0;j<2;++j)
      acc[i][j] = (f32x4_t){0.f,0.f,0.f,0.f};

  auto STAGE = [&](int kk, int buf){
    #pragma unroll
    for (int c=0;c<2;++c){
      const int i  = (c<<9) + tid;           // 16B chunk 0..1023
      const int r  = i>>3;
      const int cs = ((i&7) ^ (r&7)) << 3;   // pre-swizzled source col (T2)
      gld_lds16(xp + arow0 + (size_t)r*CC + kk + cs, &lA[buf][i<<3]);
    }
    #pragma unroll
    for (int c=0;c<2;++c){
      const int i  = (c<<9) + tid;
      const int r  = i>>3;
      const int cs = ((i&7) ^ (r&7)) << 3;
      gld_lds16(Wb + brow0 + (size_t)r*SS + kk + cs, &lB[buf][i<<3]);
    }
  };

  auto COMPUTE = [&](int buf){
    #pragma unroll
    for (int ks=0;ks<2;++ks){
      bf16x8 af[4], bfr[2];
      const int cc = (ks<<2) + lh;           // logical 16B chunk col 0..7
      #pragma unroll
      for (int mi=0;mi<4;++mi){
        const int ar = (wr<<6)+(mi<<4)+l15;
        af[mi]  = *(const bf16x8*)&lA[buf][ar*64 + ((cc ^ (ar&7))<<3)];
      }
      #pragma unroll
      for (int ni=0;ni<2;++ni){
        const int br = (wc<<5)+(ni<<4)+l15;
        bfr[ni] = *(const bf16x8*)&lB[buf][br*64 + ((cc ^ (br&7))<<3)];
      }
      #pragma unroll
      for (int mi=0;mi<4;++mi)
        #pragma unroll
        for (int ni=0;ni<2;++ni)
          acc[mi][ni] = __builtin_amdgcn_mfma_f32_16x16x32_bf16(af[mi], bfr[ni], acc[mi][ni], 0,0,0);
    }
  };

  // Prologue: both buffers' loads in flight (8 outstanding / thread).
  STAGE(0, 0);
  STAGE(64, 1);
  #pragma unroll
  for (int t=0;t<4;++t){
    if (t<3) asm volatile("s_waitcnt vmcnt(4)" ::: "memory");
    else     asm volatile("s_waitcnt vmcnt(0)" ::: "memory");
    __builtin_amdgcn_s_barrier();     // buf[t&1] fully landed (all waves)
    COMPUTE(t&1);
    __builtin_amdgcn_s_barrier();     // all waves done reading buf[t&1]
    if (t<2) STAGE((t+2)<<6, t&1);    // overwrite now-free buffer
  }

  // Epilogue: bias add + nontemporal store.
  // D layout: col=lane&15, row=(lane>>4)*4+reg.
  #pragma unroll
  for (int ni=0;ni<2;++ni){
    const int col = n0 + (wc<<5) + (ni<<4) + l15;
    const float bv = bias[col];
    #pragma unroll
    for (int mi=0;mi<4;++mi){
      const int rb = m0 + (wr<<6) + (mi<<4) + (lh<<2);
      float* op = out + (size_t)rb*NN + col;
      #pragma unroll
      for (int r=0;r<4;++r)
        __builtin_nontemporal_store(acc[mi][ni][r] + bv, op + (size_t)r*NN);
    }
  }
}

extern "C" void kernel_launch(void* const* d_in, const int* in_sizes, int n_in,
                              void* d_out, int out_size, void* d_ws, size_t ws_size,
                              hipStream_t stream) {
  const float* x    = (const float*)d_in[0];   // [B, C] f32
  const float* W    = (const float*)d_in[1];   // [G, R, S] f32
  const float* bias = (const float*)d_in[2];   // [G, R] f32
  const int*   perm = (const int*)d_in[3];     // [G, S] int32
  float* out = (float*)d_out;                  // [B, G*R] f32

  unsigned short* xp = (unsigned short*)d_ws;                            // B*C bf16 = 64 MiB
  unsigned short* Wb = (unsigned short*)((char*)d_ws + (size_t)BB*CC*2); // G*R*S bf16 = 4 MiB

  const int wblocks = (GG*RR*SS)/(256*8);      // 1024
  prep_kernel<<<dim3(BB/RPB + wblocks), dim3(256), 0, stream>>>(x, perm, W, xp, Wb);
  gemm_kernel<<<dim3(4096), dim3(512), 0, stream>>>(xp, Wb, bias, out);
}

// Round 5
// 120.223 us; speedup vs baseline: 1.2721x; 1.2721x over previous
//
#include <hip/hip_runtime.h>

// Problem constants
#define BB 8192
#define CC 4096
#define GG 16
#define SS 256
#define RR 512
#define NN (GG*RR)   // 8192 output cols

typedef __bf16 bf16x8 __attribute__((ext_vector_type(8)));
typedef float  f32x4_t __attribute__((ext_vector_type(4)));

__device__ __forceinline__ void gld_lds16(const void* g, void* l){
  __builtin_amdgcn_global_load_lds((const __attribute__((address_space(1))) void*)g,
                                   (__attribute__((address_space(3))) void*)l, 16, 0, 0);
}

// ---------------- Pass 1: fused {per-row gather+cast} and {W cast} ----------
// Blocks 0..BB-1: permute+cast one x row (R3 structure: 16KB LDS, 8 blk/CU).
// Blocks BB..BB+1023: cast one W chunk. Native bf16 casts (v_cvt_pk_bf16_f32).
__global__ void __launch_bounds__(256) prep_kernel(
    const float* __restrict__ x, const int* __restrict__ perm,
    const float* __restrict__ W,
    unsigned short* __restrict__ xp, unsigned short* __restrict__ Wb)
{
  __shared__ float row[CC];
  const int tid = threadIdx.x;
  const int bid = blockIdx.x;
  if (bid < BB) {
    const size_t b = bid;
    const float4* xr = (const float4*)(x + b*CC);
    float4* rr = (float4*)row;
    #pragma unroll
    for (int c=0;c<4;++c) rr[c*256+tid] = xr[c*256+tid];
    __syncthreads();
    unsigned short* xo = xp + b*CC;
    #pragma unroll
    for (int c=0;c<2;++c){
      const int j0 = (((c<<8)+tid)<<3);
      const int4 p0 = *(const int4*)(perm + j0);
      const int4 p1 = *(const int4*)(perm + j0 + 4);
      bf16x8 v;
      v[0]=(__bf16)row[p0.x]; v[1]=(__bf16)row[p0.y];
      v[2]=(__bf16)row[p0.z]; v[3]=(__bf16)row[p0.w];
      v[4]=(__bf16)row[p1.x]; v[5]=(__bf16)row[p1.y];
      v[6]=(__bf16)row[p1.z]; v[7]=(__bf16)row[p1.w];
      *(bf16x8*)(xo + j0) = v;
    }
  } else {
    const int i = (((bid - BB)<<8) + tid)<<3;
    const float4 f0 = ((const float4*)(W+i))[0];
    const float4 f1 = ((const float4*)(W+i))[1];
    bf16x8 v;
    v[0]=(__bf16)f0.x; v[1]=(__bf16)f0.y; v[2]=(__bf16)f0.z; v[3]=(__bf16)f0.w;
    v[4]=(__bf16)f1.x; v[5]=(__bf16)f1.y; v[6]=(__bf16)f1.z; v[7]=(__bf16)f1.w;
    *(bf16x8*)(Wb+i) = v;
  }
}

// ---------------- Pass 2: grouped GEMM, 128x128 tile, K=256 -----------------
// 8 waves (2 row x 4 col), double-buffered LDS, counted vmcnt (T4),
// LDS XOR-swizzle (T2, both-sides), XCD-bijective block map (T1).
// Cached epilogue stores (nt regressed in R4).
__global__ void __launch_bounds__(512, 4) gemm_kernel(
    const unsigned short* __restrict__ xp, const unsigned short* __restrict__ Wb,
    const float* __restrict__ bias, float* __restrict__ out)
{
  __shared__ unsigned short lA[2][128*64];
  __shared__ unsigned short lB[2][128*64];
  const int tid  = threadIdx.x;
  const int lane = tid & 63;
  const int w    = tid >> 6;
  const int wr   = w >> 2;          // 0..1  (64 out rows each)
  const int wc   = w & 3;           // 0..3  (32 out cols each)
  const int l15  = lane & 15, lh = lane >> 4;

  // XCD-aware block mapping: nwg=4096, 512 per XCD, bx-octet per XCD.
  const int bid   = blockIdx.x;
  const int xcd   = bid & 7;
  const int local = bid >> 3;                   // 0..511
  const int bx    = (xcd << 3) + (local & 7);   // 8 n-tiles = 2 groups per XCD
  const int by    = local >> 3;                 // 0..63

  const int m0 = by << 7;
  const int n0 = bx << 7;
  const int g  = bx >> 2;
  const size_t arow0 = (size_t)m0*CC + (size_t)g*SS;
  const size_t brow0 = (size_t)n0*SS;

  f32x4_t acc[4][2];
  #pragma unroll
  for (int i=0;i<4;++i)
    #pragma unroll
    for (int j=0;j<2;++j)
      acc[i][j] = (f32x4_t){0.f,0.f,0.f,0.f};

  auto STAGE = [&](int kk, int buf){
    #pragma unroll
    for (int c=0;c<2;++c){
      const int i  = (c<<9) + tid;           // 16B chunk 0..1023
      const int r  = i>>3;
      const int cs = ((i&7) ^ (r&7)) << 3;   // pre-swizzled source col (T2)
      gld_lds16(xp + arow0 + (size_t)r*CC + kk + cs, &lA[buf][i<<3]);
    }
    #pragma unroll
    for (int c=0;c<2;++c){
      const int i  = (c<<9) + tid;
      const int r  = i>>3;
      const int cs = ((i&7) ^ (r&7)) << 3;
      gld_lds16(Wb + brow0 + (size_t)r*SS + kk + cs, &lB[buf][i<<3]);
    }
  };

  auto COMPUTE = [&](int buf){
    #pragma unroll
    for (int ks=0;ks<2;++ks){
      bf16x8 af[4], bfr[2];
      const int cc = (ks<<2) + lh;           // logical 16B chunk col 0..7
      #pragma unroll
      for (int mi=0;mi<4;++mi){
        const int ar = (wr<<6)+(mi<<4)+l15;
        af[mi]  = *(const bf16x8*)&lA[buf][ar*64 + ((cc ^ (ar&7))<<3)];
      }
      #pragma unroll
      for (int ni=0;ni<2;++ni){
        const int br = (wc<<5)+(ni<<4)+l15;
        bfr[ni] = *(const bf16x8*)&lB[buf][br*64 + ((cc ^ (br&7))<<3)];
      }
      #pragma unroll
      for (int mi=0;mi<4;++mi)
        #pragma unroll
        for (int ni=0;ni<2;++ni)
          acc[mi][ni] = __builtin_amdgcn_mfma_f32_16x16x32_bf16(af[mi], bfr[ni], acc[mi][ni], 0,0,0);
    }
  };

  // Prologue: both buffers' loads in flight (8 outstanding / thread).
  STAGE(0, 0);
  STAGE(64, 1);
  #pragma unroll
  for (int t=0;t<4;++t){
    if (t<3) asm volatile("s_waitcnt vmcnt(4)" ::: "memory");
    else     asm volatile("s_waitcnt vmcnt(0)" ::: "memory");
    __builtin_amdgcn_s_barrier();     // buf[t&1] fully landed (all waves)
    COMPUTE(t&1);
    __builtin_amdgcn_s_barrier();     // all waves done reading buf[t&1]
    if (t<2) STAGE((t+2)<<6, t&1);    // overwrite now-free buffer
  }

  // Epilogue: bias add + store. D layout: col=lane&15, row=(lane>>4)*4+reg.
  #pragma unroll
  for (int ni=0;ni<2;++ni){
    const int col = n0 + (wc<<5) + (ni<<4) + l15;
    const float bv = bias[col];
    #pragma unroll
    for (int mi=0;mi<4;++mi){
      const int rb = m0 + (wr<<6) + (mi<<4) + (lh<<2);
      float* op = out + (size_t)rb*NN + col;
      #pragma unroll
      for (int r=0;r<4;++r)
        op[(size_t)r*NN] = acc[mi][ni][r] + bv;
    }
  }
}

extern "C" void kernel_launch(void* const* d_in, const int* in_sizes, int n_in,
                              void* d_out, int out_size, void* d_ws, size_t ws_size,
                              hipStream_t stream) {
  const float* x    = (const float*)d_in[0];   // [B, C] f32
  const float* W    = (const float*)d_in[1];   // [G, R, S] f32
  const float* bias = (const float*)d_in[2];   // [G, R] f32
  const int*   perm = (const int*)d_in[3];     // [G, S] int32
  float* out = (float*)d_out;                  // [B, G*R] f32

  unsigned short* xp = (unsigned short*)d_ws;                            // B*C bf16 = 64 MiB
  unsigned short* Wb = (unsigned short*)((char*)d_ws + (size_t)BB*CC*2); // G*R*S bf16 = 4 MiB

  const int wblocks = (GG*RR*SS)/(256*8);      // 1024
  prep_kernel<<<dim3(BB + wblocks), dim3(256), 0, stream>>>(x, perm, W, xp, Wb);
  gemm_kernel<<<dim3(4096), dim3(512), 0, stream>>>(xp, Wb, bias, out);
}